// Round 3
// baseline (177.214 us; speedup 1.0000x reference)
//
#include <hip/hip_runtime.h>
#include <stdint.h>

typedef unsigned long long u64;
typedef unsigned int u32;

#define CONF_T 0.9f
#define IOU_T 0.5f
#define TOPK 4096
#define SORTN 8192

// ---- workspace layout (bytes) ----
#define HIST_OFF     0          // u32[4096]      16384
#define CTR_OFF      16384      // u32[16]: [1]=thrB [2]=M
#define BINSTART_OFF 16448      // u32[4096]      16384
#define BINCUR_OFF   32832      // u32[4096]      16384
#define ROWANY_OFF   49216      // u32[4096]      16384
#define SELBOX_OFF   65600      // float4[4096]   65536 (16B aligned)
#define SELSC_OFF    131136     // float[4096]    16384
#define SELLM_OFF    147520     // float[40960]   163840
#define SORT_OFF     311360     // u64[8192]      65536
#define INTRA_OFF    376896     // u64[4096]      32768
#define MASK_OFF     409664     // u64[4096*64]   2097152

__device__ __forceinline__ int score_bin(float s) {
    u32 b = __float_as_uint(s);
    if (b >= 0x3F800000u) return 0;
    int bin = (int)((0x3F800000u - b) >> 9);
    return bin > 4095 ? 4095 : bin;
}

// K0: zero hist + ctr (replaces hipMemsetAsync in the graph)
__global__ void k_zero(u32* __restrict__ hist, u32* __restrict__ ctr) {
    int i = blockIdx.x * 256 + threadIdx.x;
    hist[i] = 0u;
    if (i < 16) ctr[i] = 0u;
}

// K1: histogram of candidate scores (score > 0.9), float4-vectorized conf scan
__global__ void k_hist(const float4* __restrict__ conf4, int N2, u32* __restrict__ hist) {
    int stride = gridDim.x * blockDim.x;
    for (int i = blockIdx.x * blockDim.x + threadIdx.x; i < N2; i += stride) {
        float4 v = conf4[i];
        if (v.y > CONF_T) atomicAdd(&hist[score_bin(v.y)], 1u);
        if (v.w > CONF_T) atomicAdd(&hist[score_bin(v.w)], 1u);
    }
}

// K2: full exclusive prefix over 4096 bins + threshold bin B + superset size M
__global__ void __launch_bounds__(256) k_scan(const u32* __restrict__ hist,
                                              u32* __restrict__ binStart,
                                              u32* __restrict__ binCur,
                                              u32* __restrict__ ctr) {
    __shared__ u32 parts[256];
    int t = threadIdx.x;
    u32 h[16];
    u32 sum = 0;
    #pragma unroll
    for (int i = 0; i < 16; i++) { h[i] = hist[t * 16 + i]; sum += h[i]; }
    parts[t] = sum;
    __syncthreads();
    for (int d = 1; d < 256; d <<= 1) {
        u32 add = (t >= d) ? parts[t - d] : 0u;
        __syncthreads();
        parts[t] += add;
        __syncthreads();
    }
    u32 incl = parts[t];
    u32 excl = incl - sum;
    u32 total = parts[255];
    u32 target = total < TOPK ? total : TOPK;
    u32 run = excl;
    #pragma unroll
    for (int i = 0; i < 16; i++) {
        binStart[t * 16 + i] = run;
        binCur[t * 16 + i] = run;
        run += h[i];
    }
    if (total == 0) {
        if (t == 0) { ctr[1] = 0xFFFFFFFFu; ctr[2] = 0u; }
        return;
    }
    if (excl < target && incl >= target) {
        u32 r2 = excl;
        for (int i = 0; i < 16; i++) {
            r2 += h[i];
            if (r2 >= target) { ctr[1] = (u32)(t * 16 + i); ctr[2] = r2; break; }
        }
    }
}

// K3: counting-sort append into per-bin segments (keys (score_bits<<32)|~idx)
__global__ void k_compact(const float4* __restrict__ conf4, int N2,
                          const u32* __restrict__ ctr, u32* __restrict__ binCur,
                          u64* __restrict__ sortbuf) {
    u32 B = ctr[1];
    int stride = gridDim.x * blockDim.x;
    for (int i = blockIdx.x * blockDim.x + threadIdx.x; i < N2; i += stride) {
        float4 v = conf4[i];
        #pragma unroll
        for (int half = 0; half < 2; half++) {
            float s = half ? v.w : v.y;
            u32 idx = (u32)(2 * i + half);
            if (s > CONF_T) {
                int bin = score_bin(s);
                if ((u32)bin <= B) {
                    u32 pos = atomicAdd(&binCur[bin], 1u);
                    if (pos < SORTN) {
                        sortbuf[pos] = ((u64)__float_as_uint(s) << 32) | (u64)(~idx);
                    }
                }
            }
        }
    }
}

// K4: exact rank within bin + decode + scatter to rank position
__global__ void __launch_bounds__(256) k_rank(
        const float4* __restrict__ loc, const float4* __restrict__ priors,
        const float* __restrict__ landm, const u64* __restrict__ sortbuf,
        const u32* __restrict__ hist, const u32* __restrict__ binStart,
        const u32* __restrict__ ctr,
        float4* __restrict__ selbox, float* __restrict__ selscore,
        float* __restrict__ sellm) {
    u32 M = ctr[2];
    if (M > SORTN) M = SORTN;
    u32 p = blockIdx.x * 256 + threadIdx.x;
    if (p >= M) return;
    u64 key = sortbuf[p];
    float sc = __uint_as_float((u32)(key >> 32));
    int bin = score_bin(sc);
    u32 st = binStart[bin];
    u32 cnt = hist[bin];
    u32 end = st + cnt;
    if (end > M) end = M;
    u32 rank = st;
    for (u32 j = st; j < end; j++) {
        rank += (sortbuf[j] > key) ? 1u : 0u;
    }
    if (rank >= TOPK) return;
    u32 idx = ~(u32)key;
    float4 L = loc[idx];
    float4 P = priors[idx];
    float cx = P.x + L.x * 0.1f * P.z;
    float cy = P.y + L.y * 0.1f * P.w;
    float wx = P.z * expf(L.z * 0.2f);
    float wy = P.w * expf(L.w * 0.2f);
    float4 bx;
    bx.x = (cx - 0.5f * wx) * 8192.f;
    bx.y = (cy - 0.5f * wy) * 8192.f;
    bx.z = (cx + 0.5f * wx) * 8192.f;
    bx.w = (cy + 0.5f * wy) * 8192.f;
    selbox[rank] = bx;
    selscore[rank] = sc;
    const float* lmr = landm + (size_t)idx * 10;
    float* lmo = sellm + (size_t)rank * 10;
    #pragma unroll
    for (int q = 0; q < 5; q++) {
        float lx = lmr[2 * q], ly = lmr[2 * q + 1];
        lmo[2 * q]     = (P.x + lx * 0.1f * P.z) * 8192.f;
        lmo[2 * q + 1] = (P.y + ly * 0.1f * P.w) * 8192.f;
    }
}

// K4b: zero-pad sel buffers for ranks >= M (data-dependent, replaces big memset)
__global__ void k_pad(const u32* __restrict__ ctr, float4* __restrict__ selbox,
                      float* __restrict__ selscore, float* __restrict__ sellm) {
    u32 M = ctr[2];
    if (M > TOPK) M = TOPK;
    u32 i = blockIdx.x * 256 + threadIdx.x;
    if (i < M || i >= TOPK) return;
    selbox[i] = make_float4(0.f, 0.f, 0.f, 0.f);
    selscore[i] = 0.f;
    #pragma unroll
    for (int q = 0; q < 10; q++) sellm[(size_t)i * 10 + q] = 0.f;
}

// K5: suppression bitmask matrix. Each wave computes one row's 64 words (w=lane).
// Also stores rowAny via ballot (no pre-zero needed) and the intra-group word.
__global__ void __launch_bounds__(256) k_mask(const float4* __restrict__ selbox,
                                              u64* __restrict__ mask,
                                              u32* __restrict__ rowAny,
                                              u64* __restrict__ intraBuf) {
    __shared__ float4 sb[TOPK];   // 64 KB
    int t = threadIdx.x, b = blockIdx.x;
    for (int i = t; i < TOPK; i += 256) sb[i] = selbox[i];
    __syncthreads();
    int row0 = b * 16;
    #pragma unroll
    for (int pp = 0; pp < 4; pp++) {
        int id = t + pp * 256;          // 0..1023
        int row = row0 + (id >> 6);
        int w = id & 63;
        u64 bits = 0ull;
        if (w * 64 + 63 > row) {
            float4 bi = sb[row];
            float ai = fmaxf(bi.z - bi.x, 0.f) * fmaxf(bi.w - bi.y, 0.f);
            int jbase = w * 64;
            for (int jj = 0; jj < 64; jj++) {
                int j = jbase + jj;
                if (j <= row) continue;
                float4 bj = sb[j];
                float aj = fmaxf(bj.z - bj.x, 0.f) * fmaxf(bj.w - bj.y, 0.f);
                float lx = fmaxf(bi.x, bj.x), ly = fmaxf(bi.y, bj.y);
                float rx = fminf(bi.z, bj.z), ry = fminf(bi.w, bj.w);
                float inter = fmaxf(rx - lx, 0.f) * fmaxf(ry - ly, 0.f);
                float iou = inter / (ai + aj - inter + 1e-12f);
                if (iou > IOU_T) bits |= 1ull << jj;
            }
        }
        mask[(size_t)row * 64 + w] = bits;
        u64 nzb = __ballot(bits != 0ull);
        if (w == 0) rowAny[row] = (nzb != 0ull) ? 1u : 0u;
        if (w == (row >> 6)) intraBuf[row] = bits;
    }
}

// K6: fused ballots + serial greedy NMS + output write. One 256-thread block.
__global__ void __launch_bounds__(256) k_nms(const u64* __restrict__ mask,
                                             const float* __restrict__ selscore,
                                             const u32* __restrict__ rowAny,
                                             const u64* __restrict__ intraBuf,
                                             const float4* __restrict__ selbox,
                                             const float* __restrict__ sellm,
                                             float* __restrict__ out) {
    __shared__ u64 intra_s[4096];   // 32 KB
    __shared__ u64 validw_s[64], nzw_s[64], keep_s[64];
    int tid = threadIdx.x;
    int wv = tid >> 6, lane = tid & 63;
    for (int i = tid; i < 4096; i += 256) intra_s[i] = intraBuf[i];
    for (int g = wv; g < 64; g += 4) {
        float s = selscore[g * 64 + lane];
        u32 ra = rowAny[g * 64 + lane];
        u64 vb = __ballot(s > CONF_T);
        u64 nb = __ballot(ra != 0u);
        if (lane == 0) { validw_s[g] = vb; nzw_s[g] = nb; }
    }
    __syncthreads();
    if (wv == 0) {
        int t = lane;
        u64 vw = validw_s[t];
        u64 nzv = nzw_s[t];
        u64 sup = 0ull, keepw = 0ull;
        for (int g = 0; g < 64; g++) {
            u64 cur = __shfl(sup, g);
            u64 validg = __shfl(vw, g);
            u64 nzg = __shfl(nzv, g);
            u64 alive = (~cur) & validg;
            if (nzg) {
                u64 intra = intra_s[g * 64 + t];
                u64 rem = nzg;
                while (rem) {
                    int bb = __ffsll((long long)rem) - 1;
                    rem &= rem - 1;
                    if ((alive >> bb) & 1ull) {
                        u64 rowb = __shfl(intra, bb);
                        alive &= ~rowb;
                    }
                }
            }
            if (t == g) keepw = alive;
            u64 srem = alive & nzg;
            while (srem) {
                int bb = __ffsll((long long)srem) - 1;
                srem &= srem - 1;
                sup |= mask[(size_t)(g * 64 + bb) * 64 + t];
            }
        }
        keep_s[t] = keepw;
    }
    __syncthreads();
    for (int i = tid; i < TOPK; i += 256) {
        bool kp = (keep_s[i >> 6] >> (i & 63)) & 1ull;
        float4 b = selbox[i];
        float* o = out + (size_t)i * 15;
        o[0] = kp ? b.x : 0.f;
        o[1] = kp ? b.y : 0.f;
        o[2] = kp ? b.z : 0.f;
        o[3] = kp ? b.w : 0.f;
        o[4] = kp ? selscore[i] : 0.f;
        #pragma unroll
        for (int q = 0; q < 10; q++) o[5 + q] = kp ? sellm[(size_t)i * 10 + q] : 0.f;
    }
}

extern "C" void kernel_launch(void* const* d_in, const int* in_sizes, int n_in,
                              void* d_out, int out_size, void* d_ws, size_t ws_size,
                              hipStream_t stream) {
    const float4* loc    = (const float4*)d_in[0];
    const float4* conf4  = (const float4*)d_in[1];
    const float*  landm  = (const float*)d_in[2];
    const float4* priors = (const float4*)d_in[3];
    float* out = (float*)d_out;
    int N = in_sizes[1] / 2;
    int N2 = N / 2;   // float4 elements (2 anchors each); N is even for this problem

    char* ws = (char*)d_ws;
    u32* hist     = (u32*)(ws + HIST_OFF);
    u32* ctr      = (u32*)(ws + CTR_OFF);
    u32* binStart = (u32*)(ws + BINSTART_OFF);
    u32* binCur   = (u32*)(ws + BINCUR_OFF);
    u32* rowAny   = (u32*)(ws + ROWANY_OFF);
    float4* selbox = (float4*)(ws + SELBOX_OFF);
    float* selsc   = (float*)(ws + SELSC_OFF);
    float* sellm   = (float*)(ws + SELLM_OFF);
    u64* sortbuf  = (u64*)(ws + SORT_OFF);
    u64* intraBuf = (u64*)(ws + INTRA_OFF);
    u64* maskp    = (u64*)(ws + MASK_OFF);

    int nb = 2048;
    k_zero<<<16, 256, 0, stream>>>(hist, ctr);
    k_hist<<<nb, 256, 0, stream>>>(conf4, N2, hist);
    k_scan<<<1, 256, 0, stream>>>(hist, binStart, binCur, ctr);
    k_compact<<<nb, 256, 0, stream>>>(conf4, N2, ctr, binCur, sortbuf);
    k_rank<<<32, 256, 0, stream>>>(loc, priors, landm, sortbuf, hist, binStart, ctr,
                                   selbox, selsc, sellm);
    k_pad<<<16, 256, 0, stream>>>(ctr, selbox, selsc, sellm);
    k_mask<<<256, 256, 0, stream>>>(selbox, maskp, rowAny, intraBuf);
    k_nms<<<1, 256, 0, stream>>>(maskp, selsc, rowAny, intraBuf, selbox, sellm, out);
}